// Round 11
// baseline (102.867 us; speedup 1.0000x reference)
//
#include <hip/hip_runtime.h>

// out[b,o,i,j] = sum_c | sum_{ti,tj<=8} K[o,0,ti,tj] * x[b,c,(i+5-ti)&127,(j+5-tj)&127] |
// B=8 C=16 H=W=128 O=32. MFMA im2col (verified R3/R5/R8/R9 math):
//   per (b,c): D[m][o] = sum_k A[m][k]*Bk[k][o], k = ti*16+tj (tj pad 16, ti pad 10)
//   A[m][k] = x[i+5-ti][j+5-tj], j = 8*m + phase.  acc += |D| over c.
// R11: LDS eliminated. xr (prep'd column-reversed bf16 with replicated wrap
//      rows) is already in per-lane window layout -> each wave loads its 10
//      windows/channel straight to registers (global_load_dwordx4, imm
//      offsets), software-pipelined one channel ahead (cur/nxt structs,
//      constant indices only). No barrier, no DMA, no staging phase.
//      Compute + epilogue byte-identical to R9 (passed, absmax 0.0625).

typedef __attribute__((ext_vector_type(8)))  short  short8;
typedef __attribute__((ext_vector_type(4)))  float  float4v;
typedef __attribute__((ext_vector_type(4)))  unsigned int uint4v;

#define XR_ROWS 138                   // 128 + 9 replicated + 1 pad
#define XR_RDW  72                    // dwords per row (144 bf16 = 288 B)
#define XR_CH_DW (XR_ROWS * XR_RDW)   // 9936 dwords per channel
#define XR_CH_B  (XR_CH_DW * 4)       // 39744 B per channel
#define XR_TOT_DW (128 * XR_CH_DW)    // 1,271,808 dwords
#define BPRE_OFF ((size_t)128 * XR_ROWS * 288)   // 5,087,232 B (16B aligned)
#define PREP_BLOCKS 2048
#define PREP_STRIDE (PREP_BLOCKS * 256)

__device__ __forceinline__ unsigned int f2bf(float f) {
    union { float f; unsigned int u; } a; a.f = f;
    unsigned int u = a.u;
    u += 0x7fffu + ((u >> 16) & 1u);   // RNE
    return u >> 16;
}

#if __has_builtin(__builtin_amdgcn_alignbit)
#define ALIGN16(hi_, lo_) __builtin_amdgcn_alignbit((hi_), (lo_), 16)
#else
#define ALIGN16(hi_, lo_) \
    (unsigned int)((((unsigned long long)(hi_) << 32) | (lo_)) >> 16)
#endif

#define FRAG_EVEN(q_) __builtin_bit_cast(short8, (uint4v){                    \
        wnd[(q_)+0], wnd[(q_)+1], wnd[(q_)+2], wnd[(q_)+3]})
#define FRAG_ODD(q_)  __builtin_bit_cast(short8, (uint4v){                    \
        ALIGN16(wnd[(q_)+1], wnd[(q_)+0]),                                    \
        ALIGN16(wnd[(q_)+2], wnd[(q_)+1]),                                    \
        ALIGN16(wnd[(q_)+3], wnd[(q_)+2]),                                    \
        ALIGN16(wnd[(q_)+4], wnd[(q_)+3])})

// ---- prep: xr = column-reversed bf16 x with replicated wrap rows; plus
//            per-lane packed B fragments (last block). Unchanged from R9/R10.
__global__ __launch_bounds__(256)
void optical_prep_69698729279498(const float* __restrict__ x,
                                 const float* __restrict__ kern,
                                 unsigned int* __restrict__ xr,
                                 uint4v* __restrict__ bpre) {
    if (blockIdx.x == PREP_BLOCKS) {
        const int l = threadIdx.x;
        if (l < 64) {
            const int lk = l & 15;
            const int g2 = l >> 4;
            for (int oh = 0; oh < 2; ++oh) {
                const int o = oh * 16 + lk;
                for (int ck = 0; ck < 5; ++ck) {
                    const int ti  = 2 * ck + (g2 >> 1);
                    const int tj0 = (g2 & 1) * 8;
                    unsigned int pk[4];
#pragma unroll
                    for (int ee = 0; ee < 4; ++ee) {
                        int tj_a = tj0 + 2 * ee, tj_b = tj_a + 1;
                        float va = (ti <= 8 && tj_a <= 8) ? kern[o * 1296 + ti * 9 + tj_a] : 0.f;
                        float vb = (ti <= 8 && tj_b <= 8) ? kern[o * 1296 + ti * 9 + tj_b] : 0.f;
                        pk[ee] = f2bf(va) | (f2bf(vb) << 16);
                    }
                    bpre[(oh * 5 + ck) * 64 + l] = (uint4v){pk[0], pk[1], pk[2], pk[3]};
                }
            }
        }
        return;
    }
    for (int idx = blockIdx.x * 256 + threadIdx.x; idx < XR_TOT_DW;
         idx += PREP_STRIDE) {
        int bc  = idx / XR_CH_DW;
        int rem = idx - bc * XR_CH_DW;
        int r   = rem / XR_RDW;
        int ccd = rem - r * XR_RDW;
        int cc  = 2 * ccd;
        const float* xp = x + (bc << 14) + ((r & 127) << 7);
        float v0 = xp[(132 - cc) & 127];
        float v1 = xp[(131 - cc) & 127];
        xr[idx] = f2bf(v0) | (f2bf(v1) << 16);
    }
}

// 10 window registers for one channel (indices always compile-time constants)
struct Win { uint4v a[5]; uint4v b[5]; };

__device__ __forceinline__ Win loadwin(const char* p) {
    Win W;
#pragma unroll
    for (int ck = 0; ck < 5; ++ck) {
        const char* q = p + (8 - 2 * ck) * 288;   // imm offsets 0..2320
        W.a[ck] = *(const uint4v*)q;
        W.b[ck] = *(const uint4v*)(q + 16);
    }
    return W;
}

// ---- main: no LDS, no barrier
__global__ __launch_bounds__(256, 2)
void optical_conv_69698729279498(const unsigned int* __restrict__ xr,
                                 const uint4v* __restrict__ bpre,
                                 float* __restrict__ out) {
    const int tid = threadIdx.x;
    const int l   = tid & 63;
    const int w   = tid >> 6;        // wave 0..3
    const int oh  = w & 1;           // o-half
    const int rh  = w >> 1;          // row within block's 2-row tile
    const int i0  = blockIdx.x * 2;  // first output row of tile
    const int b   = blockIdx.y;      // batch 0..7

    const int lk   = l & 15;         // A m-index / B,D o-index
    const int g    = (l >> 4) & 1;   // tj half for A
    const int hi32 = l >> 5;         // ti parity within chunk for A
    const int g2   = l >> 4;         // quad 0..3
    const int o    = oh * 16 + lk;

    // per-lane base: channel c chunk ck window lives at
    //   base + c*39744 + (8-2ck)*288 + {0,16}
    const int wstart = (i0 >= 4) ? (i0 - 4) : (i0 + 124);
    const char* base = (const char*)xr
                     + (size_t)(b * 16) * XR_CH_B
                     + (size_t)(wstart + 1 - hi32 + rh) * 288
                     + (240 - 16 * lk + 16 * g);

    // B fragments: 5 coalesced dwordx4 loads (this wave's o-half)
    short8 Bf[5];
#pragma unroll
    for (int ck = 0; ck < 5; ++ck)
        Bf[ck] = __builtin_bit_cast(short8, bpre[(oh * 5 + ck) * 64 + l]);

    float4v acc[8];
#pragma unroll
    for (int p = 0; p < 8; ++p) acc[p] = (float4v){0.f, 0.f, 0.f, 0.f};
    const float4v zero4 = (float4v){0.f, 0.f, 0.f, 0.f};

    Win cur = loadwin(base);
    for (int c = 0; c < 16; ++c) {
        // prefetch next channel while computing this one (clamped dup at end)
        const int cn = (c < 15) ? (c + 1) : 15;
        Win nxt = loadwin(base + (size_t)cn * XR_CH_B);

        float4v D[8];
#pragma unroll
        for (int ck = 0; ck < 5; ++ck) {
            unsigned int wnd[8] = {cur.a[ck].x, cur.a[ck].y, cur.a[ck].z, cur.a[ck].w,
                                   cur.b[ck].x, cur.b[ck].y, cur.b[ck].z, cur.b[ck].w};
            // 8 phases: frag byte offsets 14,12,10,8,6,4,2,0 -> D[0..7]
            short8 f0 = FRAG_ODD(3),  f1 = FRAG_EVEN(3);
            short8 f2 = FRAG_ODD(2),  f3 = FRAG_EVEN(2);
            short8 f4 = FRAG_ODD(1),  f5 = FRAG_EVEN(1);
            short8 f6 = FRAG_ODD(0),  f7 = FRAG_EVEN(0);
            D[0] = __builtin_amdgcn_mfma_f32_16x16x32_bf16(f0, Bf[ck], ck ? D[0] : zero4, 0, 0, 0);
            D[1] = __builtin_amdgcn_mfma_f32_16x16x32_bf16(f1, Bf[ck], ck ? D[1] : zero4, 0, 0, 0);
            D[2] = __builtin_amdgcn_mfma_f32_16x16x32_bf16(f2, Bf[ck], ck ? D[2] : zero4, 0, 0, 0);
            D[3] = __builtin_amdgcn_mfma_f32_16x16x32_bf16(f3, Bf[ck], ck ? D[3] : zero4, 0, 0, 0);
            D[4] = __builtin_amdgcn_mfma_f32_16x16x32_bf16(f4, Bf[ck], ck ? D[4] : zero4, 0, 0, 0);
            D[5] = __builtin_amdgcn_mfma_f32_16x16x32_bf16(f5, Bf[ck], ck ? D[5] : zero4, 0, 0, 0);
            D[6] = __builtin_amdgcn_mfma_f32_16x16x32_bf16(f6, Bf[ck], ck ? D[6] : zero4, 0, 0, 0);
            D[7] = __builtin_amdgcn_mfma_f32_16x16x32_bf16(f7, Bf[ck], ck ? D[7] : zero4, 0, 0, 0);
        }
#pragma unroll
        for (int p = 0; p < 8; ++p)
#pragma unroll
            for (int e = 0; e < 4; ++e) acc[p][e] += fabsf(D[p][e]);

        cur = nxt;
    }

    // ---- epilogue: lane holds o = oh*16+lk, row i0+rh, pixels j = 32g2+8e+p
    const int i = i0 + rh;
    float* ob = out + ((((size_t)(b * 32 + o)) * 128 + i) << 7);
#pragma unroll
    for (int e = 0; e < 4; ++e) {
        float4v lo = (float4v){acc[0][e], acc[1][e], acc[2][e], acc[3][e]};
        float4v hi = (float4v){acc[4][e], acc[5][e], acc[6][e], acc[7][e]};
        *(float4v*)&ob[32 * g2 + 8 * e]     = lo;
        *(float4v*)&ob[32 * g2 + 8 * e + 4] = hi;
    }
}

extern "C" void kernel_launch(void* const* d_in, const int* in_sizes, int n_in,
                              void* d_out, int out_size, void* d_ws, size_t ws_size,
                              hipStream_t stream) {
    const float* x = (const float*)d_in[0];      // [8,16,128,128]
    const float* kern = (const float*)d_in[1];   // [32,16,9,9]
    float* out = (float*)d_out;                  // [8,32,128,128]
    unsigned int* xr = (unsigned int*)d_ws;                        // 5.09 MB
    uint4v* bpre = (uint4v*)((char*)d_ws + BPRE_OFF);              // +10 KB

    hipLaunchKernelGGL(optical_prep_69698729279498, dim3(PREP_BLOCKS + 1),
                       dim3(256), 0, stream, x, kern, xr, bpre);
    hipLaunchKernelGGL(optical_conv_69698729279498, dim3(64, 8), dim3(256),
                       0, stream, xr, bpre, out);
}

// Round 12
// 94.445 us; speedup vs baseline: 1.0892x; 1.0892x over previous
//
#include <hip/hip_runtime.h>

// out[b,o,i,j] = sum_c | sum_{ti,tj<=8} K[o,0,ti,tj] * x[b,c,(i+5-ti)&127,(j+5-tj)&127] |
// B=8 C=16 H=W=128 O=32.
// R12: 32x32x16 MFMA im2col. Per (b,c), chunk = one tap-row ti (K=16, tj pad
//   9->16): D[m][o] += A[m][tj]*K[o,ti,tj]; m = 16r + jm encodes (row i0+r,
//   pixel j = 8*jm + p). 9 chunks (no ti padding) x 8 phases, N=32 in one MFMA.
//   A lane map (m=l&31, k=8*(l>>5)+j) keeps R9's verified byte layout:
//   window base 240-16*(l&15)+16*(l>>5), row (9-ti+((l>>4)&1))*288; same
//   FRAG_ODD/EVEN alignbit extraction (R9-verified). D map (m74/m101):
//   col=lane&31, row=(reg&3)+8*(reg>>2)+4*(lane>>5).
//   Waves: ph-half x cg-half (4/block); cg-reduction + transpose via
//   stride-129 LDS out-tile (conflict-free), coalesced float4 flush.
//   Staging DMA + xr layout byte-identical to R8-R11 (verified).
//   Spill tell: WRITE_SIZE > 16384 KB.

typedef __attribute__((ext_vector_type(8)))  short  short8;
typedef __attribute__((ext_vector_type(16))) float  float16v;
typedef __attribute__((ext_vector_type(4)))  float  float4v;
typedef __attribute__((ext_vector_type(4)))  unsigned int uint4v;

#define XR_ROWS 138                   // 128 + 9 replicated + 1 pad
#define XR_RDW  72                    // dwords per row (144 bf16 = 288 B)
#define XR_CH_DW (XR_ROWS * XR_RDW)   // 9936 dwords per channel
#define XR_CH_B  (XR_CH_DW * 4)       // 39744 B per channel
#define BPRE_OFF ((size_t)128 * XR_ROWS * 288)   // 5,087,232 B (16B aligned)
#define CHB 3168                      // LDS bytes per channel (11 rows x 288)

__device__ __forceinline__ unsigned int f2bf(float f) {
    union { float f; unsigned int u; } a; a.f = f;
    unsigned int u = a.u;
    u += 0x7fffu + ((u >> 16) & 1u);   // RNE
    return u >> 16;
}

#if __has_builtin(__builtin_amdgcn_alignbit)
#define ALIGN16(hi_, lo_) __builtin_amdgcn_alignbit((hi_), (lo_), 16)
#else
#define ALIGN16(hi_, lo_) \
    (unsigned int)((((unsigned long long)(hi_) << 32) | (lo_)) >> 16)
#endif

#define FRAG_EVEN(q_) __builtin_bit_cast(short8, (uint4v){                    \
        wnd[(q_)+0], wnd[(q_)+1], wnd[(q_)+2], wnd[(q_)+3]})
#define FRAG_ODD(q_)  __builtin_bit_cast(short8, (uint4v){                    \
        ALIGN16(wnd[(q_)+1], wnd[(q_)+0]),                                    \
        ALIGN16(wnd[(q_)+2], wnd[(q_)+1]),                                    \
        ALIGN16(wnd[(q_)+3], wnd[(q_)+2]),                                    \
        ALIGN16(wnd[(q_)+4], wnd[(q_)+3])})

__device__ __forceinline__ void gload_lds16(const void* g, void* l) {
    __builtin_amdgcn_global_load_lds(
        (const __attribute__((address_space(1))) unsigned int*)g,
        (__attribute__((address_space(3))) unsigned int*)l, 16, 0, 0);
}

// ---- prep: xr = column-reversed bf16 x with replicated wrap rows (divide-
//      light grid mapping); bpre = per-lane 32x32x16 B-frags (block x=39,y=0).
__global__ __launch_bounds__(256)
void optical_prep_69698729279498(const float* __restrict__ x,
                                 const float* __restrict__ kern,
                                 unsigned int* __restrict__ xr,
                                 uint4v* __restrict__ bpre) {
    const int t = blockIdx.x * 256 + threadIdx.x;
    const int bc = blockIdx.y;
    const int rem = t - 9984;          // bx==39 => t in [9984,10240)
    if (t < XR_CH_DW) {
        int r   = t / 72;              // magic-mul division
        int ccd = t - r * 72;
        int cc  = 2 * ccd;
        const float* xp = x + (bc << 14) + ((r & 127) << 7);
        float v0 = xp[(132 - cc) & 127];
        float v1 = xp[(131 - cc) & 127];
        xr[(size_t)bc * XR_CH_DW + t] = f2bf(v0) | (f2bf(v1) << 16);
    } else if (bc == 0 && rem >= 0 && rem < 64) {
        const int l  = rem;
        const int o  = l & 31;
        const int hi = l >> 5;
        for (int ti = 0; ti < 9; ++ti) {
            unsigned int pk[4];
#pragma unroll
            for (int ee = 0; ee < 4; ++ee) {
                int tj_a = 8 * hi + 2 * ee, tj_b = tj_a + 1;
                float va = (tj_a <= 8) ? kern[o * 1296 + ti * 9 + tj_a] : 0.f;
                float vb = (tj_b <= 8) ? kern[o * 1296 + ti * 9 + tj_b] : 0.f;
                pk[ee] = f2bf(va) | (f2bf(vb) << 16);
            }
            bpre[ti * 64 + l] = (uint4v){pk[0], pk[1], pk[2], pk[3]};
        }
    }
}

// ---- main
__global__ __launch_bounds__(256, 2)
void optical_conv_69698729279498(const unsigned int* __restrict__ xr,
                                 const uint4v* __restrict__ bpre,
                                 float* __restrict__ out) {
    __shared__ __align__(16) unsigned short ldsb[16 * (CHB / 2)];  // 50688 B

    const int tid = threadIdx.x;
    const int l   = tid & 63;
    const int w   = tid >> 6;        // wave 0..3
    const int ph  = w & 1;           // phase half: p = 4*ph + pp
    const int cg  = w >> 1;          // channel group 0..1
    const int i0  = blockIdx.x * 2;  // first output row of tile
    const int b   = blockIdx.y;      // batch 0..7

    const int jm  = l & 15;          // A m: m = 16*rl + jm
    const int rl  = (l >> 4) & 1;    // row within 2-row tile (per-lane!)
    const int hi  = l >> 5;          // k half: tj = 8*hi + j

    // ---- staging: wave w DMAs channels 4w..4w+3 (verified R8-R11)
    const int wstart = (i0 >= 4) ? (i0 - 4) : (i0 + 124);
    const char* xr8 = (const char*)xr;
#pragma unroll
    for (int cw = 0; cw < 4; ++cw) {
        const int ch = 4 * w + cw;
        const char* src = xr8 + ((size_t)((b * 16 + ch) * XR_ROWS + wstart)) * 288;
        char* dst = (char*)ldsb + ch * CHB;
        gload_lds16(src + 0 * 1024 + l * 16, dst + 0 * 1024);
        gload_lds16(src + 1 * 1024 + l * 16, dst + 1 * 1024);
        gload_lds16(src + 2 * 1024 + l * 16, dst + 2 * 1024);
        if (l < 6)   // tail: 3168 - 3072 = 96 B
            gload_lds16(src + 3072 + l * 16, dst + 3072);
    }

    // ---- B fragments: 9 coalesced dwordx4 loads (all 32 o per lane)
    short8 Bf[9];
#pragma unroll
    for (int ti = 0; ti < 9; ++ti)
        Bf[ti] = __builtin_bit_cast(short8, bpre[ti * 64 + l]);

    __syncthreads();   // staging barrier (drains global_load_lds queue)

    float16v acc[4];
#pragma unroll
    for (int pp = 0; pp < 4; ++pp)
#pragma unroll
        for (int e = 0; e < 16; ++e) acc[pp][e] = 0.f;
    float16v zero16;
#pragma unroll
    for (int e = 0; e < 16; ++e) zero16[e] = 0.f;

    // per-lane base: chunk ti of channel c at lb + c*CHB + (8-ti)*288
    const char* lb = (const char*)ldsb
                   + (240 - 16 * jm + 16 * hi) + (1 + rl) * 288
                   + cg * 8 * CHB;

    for (int c = 0; c < 8; ++c) {
        float16v D[4];
#pragma unroll
        for (int ti = 0; ti < 9; ++ti) {
            const char* p = lb + (8 - ti) * 288;
            uint4v w0 = *(const uint4v*)p;
            uint4v w1 = *(const uint4v*)(p + 16);
            unsigned int wnd[8] = {w0.x, w0.y, w0.z, w0.w,
                                   w1.x, w1.y, w1.z, w1.w};
            short8 f0, f1, f2, f3;
            if (ph == 0) {   // p=0..3 -> frag byte offsets 14,12,10,8
                f0 = FRAG_ODD(3);  f1 = FRAG_EVEN(3);
                f2 = FRAG_ODD(2);  f3 = FRAG_EVEN(2);
            } else {         // p=4..7 -> frag byte offsets 6,4,2,0
                f0 = FRAG_ODD(1);  f1 = FRAG_EVEN(1);
                f2 = FRAG_ODD(0);  f3 = FRAG_EVEN(0);
            }
            D[0] = __builtin_amdgcn_mfma_f32_32x32x16_bf16(f0, Bf[ti], ti ? D[0] : zero16, 0, 0, 0);
            D[1] = __builtin_amdgcn_mfma_f32_32x32x16_bf16(f1, Bf[ti], ti ? D[1] : zero16, 0, 0, 0);
            D[2] = __builtin_amdgcn_mfma_f32_32x32x16_bf16(f2, Bf[ti], ti ? D[2] : zero16, 0, 0, 0);
            D[3] = __builtin_amdgcn_mfma_f32_32x32x16_bf16(f3, Bf[ti], ti ? D[3] : zero16, 0, 0, 0);
        }
#pragma unroll
        for (int pp = 0; pp < 4; ++pp)
#pragma unroll
            for (int e = 0; e < 16; ++e) acc[pp][e] += fabsf(D[pp][e]);
        lb += CHB;
    }

    // ---- cg-reduce + transpose via stride-129 LDS out-tile (conflict-free:
    //      129 = 1 mod 32), then coalesced float4 flush.
    // idx(lane,reg,p) = (r*32+o)*129 + 8*jm' + p,  r=reg>>3, o=l&31,
    // jm' = (reg&3) + 8*((reg>>2)&1) + 4*(l>>5)  [verified D map m74/m101]
    __syncthreads();   // all x-tile reads done; safe to overwrite ldsb
    float* otile = (float*)ldsb;
    const int obase_l = (l & 31) * 129 + 32 * (l >> 5) + 4 * ph;
    if (cg == 1) {
#pragma unroll
        for (int pp = 0; pp < 4; ++pp)
#pragma unroll
            for (int reg = 0; reg < 16; ++reg)
                otile[obase_l + (reg >> 3) * 4128 + 8 * (reg & 3)
                      + 64 * ((reg >> 2) & 1) + pp] = acc[pp][reg];
    }
    __syncthreads();
    if (cg == 0) {
#pragma unroll
        for (int pp = 0; pp < 4; ++pp)
#pragma unroll
            for (int reg = 0; reg < 16; ++reg) {
                const int idx = obase_l + (reg >> 3) * 4128 + 8 * (reg & 3)
                              + 64 * ((reg >> 2) & 1) + pp;
                otile[idx] += acc[pp][reg];
            }
    }
    __syncthreads();

    // flush: pair = r*32+o (64 pairs), 4 threads/pair cover 128 floats
    {
        const int pair = tid >> 2;     // 0..63
        const int q    = tid & 3;      // 32-float quarter
        const int r    = pair >> 5;
        const int o    = pair & 31;
        const float* src = otile + pair * 129 + q * 32;
        float* dstg = out + ((((size_t)(b * 32 + o)) * 128 + (i0 + r)) << 7) + q * 32;
#pragma unroll
        for (int k4 = 0; k4 < 8; ++k4) {
            float4v v = (float4v){src[4 * k4], src[4 * k4 + 1],
                                  src[4 * k4 + 2], src[4 * k4 + 3]};
            *(float4v*)&dstg[4 * k4] = v;
        }
    }
}

extern "C" void kernel_launch(void* const* d_in, const int* in_sizes, int n_in,
                              void* d_out, int out_size, void* d_ws, size_t ws_size,
                              hipStream_t stream) {
    const float* x = (const float*)d_in[0];      // [8,16,128,128]
    const float* kern = (const float*)d_in[1];   // [32,16,9,9]
    float* out = (float*)d_out;                  // [8,32,128,128]
    unsigned int* xr = (unsigned int*)d_ws;                        // 5.09 MB
    uint4v* bpre = (uint4v*)((char*)d_ws + BPRE_OFF);              // +9.2 KB

    hipLaunchKernelGGL(optical_prep_69698729279498, dim3(40, 128),
                       dim3(256), 0, stream, x, kern, xr, bpre);
    hipLaunchKernelGGL(optical_conv_69698729279498, dim3(64, 8), dim3(256),
                       0, stream, xr, bpre, out);
}